// Round 5
// baseline (14.050 us; speedup 1.0000x reference)
//
#include <hip/hip_runtime.h>

// H1 arm forward kinematics, elementwise over B = 2097152.
// out[i] = offset + (-U - F*ce)*col3(R_sh) + (-F*se)*col1(R_sh)
// col3(R_sh) = [sp*cr, -sr, cp*cr]          (yaw drops out of the elbow term)
// col1(R_sh) = [cp*cy + sp*sr*sy, cr*sy, -sp*cy + cp*sr*sy]
//
// R2: LDS store-transpose, 4 elem/thread -> 14.5 us.
// R4: 8 elem/thread, 1 barrier, 6 coalesced NT stores -> 11.75 us.
// R5: drop the nontemporal hint. Steady-state replays overwrite the same
//     24 MB output and re-read the same 32 MB inputs -> both L3-resident;
//     NT (no-allocate) was defeating Infinity-Cache write absorption.

typedef float f32x4 __attribute__((ext_vector_type(4)));

#define KTORSO_H    0.42999f
#define KSHOULDER_W 0.3107f
#define KUPPER_ARM  0.19886f
#define KFOREARM    0.3f

__device__ __forceinline__ void kin1(float pitch, float roll, float yaw, float elbow,
                                     float& ox, float& oy, float& oz) {
    float sp, cp, sr, cr, sy, cy, se, ce;
    __sincosf(pitch, &sp, &cp);
    __sincosf(roll,  &sr, &cr);
    __sincosf(yaw,   &sy, &cy);
    __sincosf(elbow, &se, &ce);

    float a1x = cp * cy + sp * sr * sy;
    float a1y = cr * sy;
    float a1z = -sp * cy + cp * sr * sy;

    float a3x = sp * cr;
    float a3y = -sr;
    float a3z = cp * cr;

    float k3 = -KUPPER_ARM - KFOREARM * ce;   // coefficient on col3
    float k1 = -KFOREARM * se;                // coefficient on col1

    ox = k3 * a3x + k1 * a1x;                 // offset.x = 0
    oy = KSHOULDER_W + k3 * a3y + k1 * a1y;
    oz = KTORSO_H    + k3 * a3z + k1 * a1z;
}

__device__ __forceinline__ void kin4(const f32x4& p, const f32x4& r,
                                     const f32x4& y, const f32x4& e,
                                     f32x4* dst) {  // dst[0..2]
    float o[12];
    kin1(p.x, r.x, y.x, e.x, o[0], o[1], o[2]);
    kin1(p.y, r.y, y.y, e.y, o[3], o[4], o[5]);
    kin1(p.z, r.z, y.z, e.z, o[6], o[7], o[8]);
    kin1(p.w, r.w, y.w, e.w, o[9], o[10], o[11]);
    dst[0] = (f32x4){o[0], o[1], o[2], o[3]};
    dst[1] = (f32x4){o[4], o[5], o[6], o[7]};
    dst[2] = (f32x4){o[8], o[9], o[10], o[11]};
}

__global__ __launch_bounds__(256) void h1_kin_kernel(
    const f32x4* __restrict__ qp4,
    const f32x4* __restrict__ qr4,
    const f32x4* __restrict__ qy4,
    const f32x4* __restrict__ qe4,
    f32x4* __restrict__ out4,
    int n4)  // n4 = B/4
{
    __shared__ f32x4 lds4[1536];  // 256 threads * 6 float4 = 24 KB

    int t = threadIdx.x;
    long blk = (long)blockIdx.x * 512;      // this block's float4-input span
    int iA = (int)blk + t;                  // sweep A
    int iB = iA + 256;                      // sweep B

    // Issue all 8 loads up front (deep VMEM queue).
    f32x4 pA = qp4[iA], pB = qp4[iB];
    f32x4 rA = qr4[iA], rB = qr4[iB];
    f32x4 yA = qy4[iA], yB = qy4[iB];
    f32x4 eA = qe4[iA], eB = qe4[iB];

    f32x4 dA[3], dB[3];
    kin4(pA, rA, yA, eA, dA);
    kin4(pB, rB, yB, eB, dB);

    // Stage. Phase A occupies lds4[0..768), phase B lds4[768..1536).
    // Write stride 48B/lane -> spreads across banks (min aliasing).
    #pragma unroll
    for (int k = 0; k < 3; ++k) {
        lds4[t * 3 + k]       = dA[k];
        lds4[768 + t * 3 + k] = dB[k];
    }

    __syncthreads();

    // Coalesced cached stores: 6 x 1024B-contiguous wave instructions.
    // Plain (allocating) stores let L2/L3 absorb the steady-state stream.
    long base = (long)blockIdx.x * 1536;
    #pragma unroll
    for (int k = 0; k < 6; ++k) {
        out4[base + k * 256 + t] = lds4[k * 256 + t];
    }
}

extern "C" void kernel_launch(void* const* d_in, const int* in_sizes, int n_in,
                              void* d_out, int out_size, void* d_ws, size_t ws_size,
                              hipStream_t stream) {
    const float* qp = (const float*)d_in[0];
    const float* qr = (const float*)d_in[1];
    const float* qy = (const float*)d_in[2];
    const float* qe = (const float*)d_in[3];
    float* out = (float*)d_out;

    int n = in_sizes[0];        // B = 2097152
    int n4 = n / 4;             // 524288 float4 per input
    int block = 256;
    int grid = n4 / (block * 2);  // 1024 blocks, 8 elements/thread

    h1_kin_kernel<<<grid, block, 0, stream>>>(
        (const f32x4*)qp, (const f32x4*)qr, (const f32x4*)qy, (const f32x4*)qe,
        (f32x4*)out, n4);
}

// Round 6
// 12.657 us; speedup vs baseline: 1.1101x; 1.1101x over previous
//
#include <hip/hip_runtime.h>

// H1 arm forward kinematics, elementwise over B = 2097152.
// out[i] = offset + (-U - F*ce)*col3(R_sh) + (-F*se)*col1(R_sh)
// col3(R_sh) = [sp*cr, -sr, cp*cr]          (yaw drops out of the elbow term)
// col1(R_sh) = [cp*cy + sp*sr*sy, cr*sy, -sp*cy + cp*sr*sy]
//
// R2: LDS store-transpose, 4 elem/thread -> 14.5 us.
// R4: 8 elem/thread, 1 barrier, 6 coalesced NT stores -> 11.75 us.
// R5: cached stores -> 14.05 us (REGRESSION: write stream goes to HBM;
//     cached dirty lines churn L2, NT streams straight out). NT is right.
// R6: revert to R4 + nontemporal LOADS too (inputs read once per replay;
//     don't pollute L2 the write-combiner wants).

typedef float f32x4 __attribute__((ext_vector_type(4)));

#define KTORSO_H    0.42999f
#define KSHOULDER_W 0.3107f
#define KUPPER_ARM  0.19886f
#define KFOREARM    0.3f

__device__ __forceinline__ void kin1(float pitch, float roll, float yaw, float elbow,
                                     float& ox, float& oy, float& oz) {
    float sp, cp, sr, cr, sy, cy, se, ce;
    __sincosf(pitch, &sp, &cp);
    __sincosf(roll,  &sr, &cr);
    __sincosf(yaw,   &sy, &cy);
    __sincosf(elbow, &se, &ce);

    float a1x = cp * cy + sp * sr * sy;
    float a1y = cr * sy;
    float a1z = -sp * cy + cp * sr * sy;

    float a3x = sp * cr;
    float a3y = -sr;
    float a3z = cp * cr;

    float k3 = -KUPPER_ARM - KFOREARM * ce;   // coefficient on col3
    float k1 = -KFOREARM * se;                // coefficient on col1

    ox = k3 * a3x + k1 * a1x;                 // offset.x = 0
    oy = KSHOULDER_W + k3 * a3y + k1 * a1y;
    oz = KTORSO_H    + k3 * a3z + k1 * a1z;
}

__device__ __forceinline__ void kin4(const f32x4& p, const f32x4& r,
                                     const f32x4& y, const f32x4& e,
                                     f32x4* dst) {  // dst[0..2]
    float o[12];
    kin1(p.x, r.x, y.x, e.x, o[0], o[1], o[2]);
    kin1(p.y, r.y, y.y, e.y, o[3], o[4], o[5]);
    kin1(p.z, r.z, y.z, e.z, o[6], o[7], o[8]);
    kin1(p.w, r.w, y.w, e.w, o[9], o[10], o[11]);
    dst[0] = (f32x4){o[0], o[1], o[2], o[3]};
    dst[1] = (f32x4){o[4], o[5], o[6], o[7]};
    dst[2] = (f32x4){o[8], o[9], o[10], o[11]};
}

__global__ __launch_bounds__(256) void h1_kin_kernel(
    const f32x4* __restrict__ qp4,
    const f32x4* __restrict__ qr4,
    const f32x4* __restrict__ qy4,
    const f32x4* __restrict__ qe4,
    f32x4* __restrict__ out4,
    int n4)  // n4 = B/4
{
    __shared__ f32x4 lds4[1536];  // 256 threads * 6 float4 = 24 KB

    int t = threadIdx.x;
    long blk = (long)blockIdx.x * 512;      // this block's float4-input span
    int iA = (int)blk + t;                  // sweep A
    int iB = iA + 256;                      // sweep B

    // Issue all 8 loads up front (deep VMEM queue), nontemporal (read-once).
    f32x4 pA = __builtin_nontemporal_load(&qp4[iA]);
    f32x4 pB = __builtin_nontemporal_load(&qp4[iB]);
    f32x4 rA = __builtin_nontemporal_load(&qr4[iA]);
    f32x4 rB = __builtin_nontemporal_load(&qr4[iB]);
    f32x4 yA = __builtin_nontemporal_load(&qy4[iA]);
    f32x4 yB = __builtin_nontemporal_load(&qy4[iB]);
    f32x4 eA = __builtin_nontemporal_load(&qe4[iA]);
    f32x4 eB = __builtin_nontemporal_load(&qe4[iB]);

    f32x4 dA[3], dB[3];
    kin4(pA, rA, yA, eA, dA);
    kin4(pB, rB, yB, eB, dB);

    // Stage. Phase A occupies lds4[0..768), phase B lds4[768..1536).
    // Write stride 48B/lane -> spreads across banks (min aliasing).
    #pragma unroll
    for (int k = 0; k < 3; ++k) {
        lds4[t * 3 + k]       = dA[k];
        lds4[768 + t * 3 + k] = dB[k];
    }

    __syncthreads();

    // Coalesced nontemporal stores: 6 x 1024B-contiguous wave instructions.
    long base = (long)blockIdx.x * 1536;
    #pragma unroll
    for (int k = 0; k < 6; ++k) {
        __builtin_nontemporal_store(lds4[k * 256 + t], &out4[base + k * 256 + t]);
    }
}

extern "C" void kernel_launch(void* const* d_in, const int* in_sizes, int n_in,
                              void* d_out, int out_size, void* d_ws, size_t ws_size,
                              hipStream_t stream) {
    const float* qp = (const float*)d_in[0];
    const float* qr = (const float*)d_in[1];
    const float* qy = (const float*)d_in[2];
    const float* qe = (const float*)d_in[3];
    float* out = (float*)d_out;

    int n = in_sizes[0];        // B = 2097152
    int n4 = n / 4;             // 524288 float4 per input
    int block = 256;
    int grid = n4 / (block * 2);  // 1024 blocks, 8 elements/thread

    h1_kin_kernel<<<grid, block, 0, stream>>>(
        (const f32x4*)qp, (const f32x4*)qr, (const f32x4*)qy, (const f32x4*)qe,
        (f32x4*)out, n4);
}

// Round 7
// 12.286 us; speedup vs baseline: 1.1436x; 1.0302x over previous
//
#include <hip/hip_runtime.h>

// H1 arm forward kinematics, elementwise over B = 2097152.
// out[i] = offset + (-U - F*ce)*col3(R_sh) + (-F*se)*col1(R_sh)
// col3(R_sh) = [sp*cr, -sr, cp*cr]          (yaw drops out of the elbow term)
// col1(R_sh) = [cp*cy + sp*sr*sy, cr*sy, -sp*cy + cp*sr*sy]
//
// Cache-policy matrix (measured): cached loads + NT stores = 11.75 (R4) <
// NT/NT = 12.66 (R6) < cached/cached = 14.05 (R5). Inputs are L3-resident
// across replays (want caching); output stream goes to HBM (wants NT).
// R7: R4 policy + wave-local transpose (no __syncthreads). Wave w's sweep
// produces a contiguous 192-float4 output chunk, so staging is per-wave;
// store-A overlaps compute-B.

typedef float f32x4 __attribute__((ext_vector_type(4)));

#define KTORSO_H    0.42999f
#define KSHOULDER_W 0.3107f
#define KUPPER_ARM  0.19886f
#define KFOREARM    0.3f

__device__ __forceinline__ void kin1(float pitch, float roll, float yaw, float elbow,
                                     float& ox, float& oy, float& oz) {
    float sp, cp, sr, cr, sy, cy, se, ce;
    __sincosf(pitch, &sp, &cp);
    __sincosf(roll,  &sr, &cr);
    __sincosf(yaw,   &sy, &cy);
    __sincosf(elbow, &se, &ce);

    float a1x = cp * cy + sp * sr * sy;
    float a1y = cr * sy;
    float a1z = -sp * cy + cp * sr * sy;

    float a3x = sp * cr;
    float a3y = -sr;
    float a3z = cp * cr;

    float k3 = -KUPPER_ARM - KFOREARM * ce;   // coefficient on col3
    float k1 = -KFOREARM * se;                // coefficient on col1

    ox = k3 * a3x + k1 * a1x;                 // offset.x = 0
    oy = KSHOULDER_W + k3 * a3y + k1 * a1y;
    oz = KTORSO_H    + k3 * a3z + k1 * a1z;
}

__device__ __forceinline__ void kin4(const f32x4& p, const f32x4& r,
                                     const f32x4& y, const f32x4& e,
                                     f32x4* dst) {  // dst[0..2]
    float o[12];
    kin1(p.x, r.x, y.x, e.x, o[0], o[1], o[2]);
    kin1(p.y, r.y, y.y, e.y, o[3], o[4], o[5]);
    kin1(p.z, r.z, y.z, e.z, o[6], o[7], o[8]);
    kin1(p.w, r.w, y.w, e.w, o[9], o[10], o[11]);
    dst[0] = (f32x4){o[0], o[1], o[2], o[3]};
    dst[1] = (f32x4){o[4], o[5], o[6], o[7]};
    dst[2] = (f32x4){o[8], o[9], o[10], o[11]};
}

__global__ __launch_bounds__(256) void h1_kin_kernel(
    const f32x4* __restrict__ qp4,
    const f32x4* __restrict__ qr4,
    const f32x4* __restrict__ qy4,
    const f32x4* __restrict__ qe4,
    f32x4* __restrict__ out4,
    int n4)  // n4 = B/4
{
    __shared__ f32x4 lds4[1536];  // 4 waves * 2 sweeps * 192 float4 = 24 KB

    int t    = threadIdx.x;
    int lane = t & 63;
    int w    = t >> 6;
    long blk = (long)blockIdx.x * 512;      // block's float4-input span
    int iA = (int)blk + t;                  // sweep A
    int iB = iA + 256;                      // sweep B

    // Issue all 8 loads up front (deep VMEM queue); cached (inputs are
    // L3-resident across replays).
    f32x4 pA = qp4[iA], pB = qp4[iB];
    f32x4 rA = qr4[iA], rB = qr4[iB];
    f32x4 yA = qy4[iA], yB = qy4[iB];
    f32x4 eA = qe4[iA], eB = qe4[iB];

    // Per-wave LDS regions: wave w uses [w*384, w*384+192) for A,
    // [w*384+192, w*384+384) for B. No __syncthreads needed — all
    // exchange is within one wave (lgkmcnt ordering is automatic).
    f32x4* regA = &lds4[w * 384];
    f32x4* regB = regA + 192;

    // ---- sweep A: compute, stage, store (wave-local) ----
    f32x4 dA[3];
    kin4(pA, rA, yA, eA, dA);
    #pragma unroll
    for (int k = 0; k < 3; ++k) regA[lane * 3 + k] = dA[k];

    long baseA = 3 * (blk + 64 * w);        // contiguous 192-float4 chunk
    #pragma unroll
    for (int k = 0; k < 3; ++k)
        __builtin_nontemporal_store(regA[k * 64 + lane], &out4[baseA + k * 64 + lane]);

    // ---- sweep B: compute (overlaps A's stores), stage, store ----
    f32x4 dB[3];
    kin4(pB, rB, yB, eB, dB);
    #pragma unroll
    for (int k = 0; k < 3; ++k) regB[lane * 3 + k] = dB[k];

    long baseB = 3 * (blk + 256 + 64 * w);
    #pragma unroll
    for (int k = 0; k < 3; ++k)
        __builtin_nontemporal_store(regB[k * 64 + lane], &out4[baseB + k * 64 + lane]);
}

extern "C" void kernel_launch(void* const* d_in, const int* in_sizes, int n_in,
                              void* d_out, int out_size, void* d_ws, size_t ws_size,
                              hipStream_t stream) {
    const float* qp = (const float*)d_in[0];
    const float* qr = (const float*)d_in[1];
    const float* qy = (const float*)d_in[2];
    const float* qe = (const float*)d_in[3];
    float* out = (float*)d_out;

    int n = in_sizes[0];        // B = 2097152
    int n4 = n / 4;             // 524288 float4 per input
    int block = 256;
    int grid = n4 / (block * 2);  // 1024 blocks, 8 elements/thread

    h1_kin_kernel<<<grid, block, 0, stream>>>(
        (const f32x4*)qp, (const f32x4*)qr, (const f32x4*)qy, (const f32x4*)qe,
        (f32x4*)out, n4);
}

// Round 8
// 11.362 us; speedup vs baseline: 1.2366x; 1.0813x over previous
//
#include <hip/hip_runtime.h>

// H1 arm forward kinematics, elementwise over B = 2097152.
// out[i] = offset + (-U - F*ce)*col3(R_sh) + (-F*se)*col1(R_sh)
// col3(R_sh) = [sp*cr, -sr, cp*cr]          (yaw drops out of the elbow term)
// col1(R_sh) = [cp*cy + sp*sr*sy, cr*sy, -sp*cy + cp*sr*sy]
//
// Measured ladder:
//   R1 scalar-ish stores        17.7 us
//   R2 LDS transpose, 4/thr     14.5 us
//   R4 8/thr + NT stores        11.75 us  <- BEST, this file
//   R5 cached stores            14.05 us  (write stream wants NT)
//   R6 NT loads                 12.66 us  (inputs want caching)
//   R7 no-barrier wave-local    12.29 us  (barrier convoy is actually fine)
// Conclusion: memory-bound local optimum; kernel-proper ~9.5-10 us vs 8.4 us
// pure-stream scaling of the 56 MB traffic. Revert to R4.

typedef float f32x4 __attribute__((ext_vector_type(4)));

#define KTORSO_H    0.42999f
#define KSHOULDER_W 0.3107f
#define KUPPER_ARM  0.19886f
#define KFOREARM    0.3f

__device__ __forceinline__ void kin1(float pitch, float roll, float yaw, float elbow,
                                     float& ox, float& oy, float& oz) {
    float sp, cp, sr, cr, sy, cy, se, ce;
    __sincosf(pitch, &sp, &cp);
    __sincosf(roll,  &sr, &cr);
    __sincosf(yaw,   &sy, &cy);
    __sincosf(elbow, &se, &ce);

    float a1x = cp * cy + sp * sr * sy;
    float a1y = cr * sy;
    float a1z = -sp * cy + cp * sr * sy;

    float a3x = sp * cr;
    float a3y = -sr;
    float a3z = cp * cr;

    float k3 = -KUPPER_ARM - KFOREARM * ce;   // coefficient on col3
    float k1 = -KFOREARM * se;                // coefficient on col1

    ox = k3 * a3x + k1 * a1x;                 // offset.x = 0
    oy = KSHOULDER_W + k3 * a3y + k1 * a1y;
    oz = KTORSO_H    + k3 * a3z + k1 * a1z;
}

__device__ __forceinline__ void kin4(const f32x4& p, const f32x4& r,
                                     const f32x4& y, const f32x4& e,
                                     f32x4* dst) {  // dst[0..2]
    float o[12];
    kin1(p.x, r.x, y.x, e.x, o[0], o[1], o[2]);
    kin1(p.y, r.y, y.y, e.y, o[3], o[4], o[5]);
    kin1(p.z, r.z, y.z, e.z, o[6], o[7], o[8]);
    kin1(p.w, r.w, y.w, e.w, o[9], o[10], o[11]);
    dst[0] = (f32x4){o[0], o[1], o[2], o[3]};
    dst[1] = (f32x4){o[4], o[5], o[6], o[7]};
    dst[2] = (f32x4){o[8], o[9], o[10], o[11]};
}

__global__ __launch_bounds__(256) void h1_kin_kernel(
    const f32x4* __restrict__ qp4,
    const f32x4* __restrict__ qr4,
    const f32x4* __restrict__ qy4,
    const f32x4* __restrict__ qe4,
    f32x4* __restrict__ out4,
    int n4)  // n4 = B/4
{
    __shared__ f32x4 lds4[1536];  // 256 threads * 6 float4 = 24 KB

    int t = threadIdx.x;
    long blk = (long)blockIdx.x * 512;      // this block's float4-input span
    int iA = (int)blk + t;                  // sweep A
    int iB = iA + 256;                      // sweep B

    // Issue all 8 loads up front (deep VMEM queue); cached (inputs are
    // re-read every replay and L2/L3-friendly).
    f32x4 pA = qp4[iA], pB = qp4[iB];
    f32x4 rA = qr4[iA], rB = qr4[iB];
    f32x4 yA = qy4[iA], yB = qy4[iB];
    f32x4 eA = qe4[iA], eB = qe4[iB];

    f32x4 dA[3], dB[3];
    kin4(pA, rA, yA, eA, dA);
    kin4(pB, rB, yB, eB, dB);

    // Stage. Phase A occupies lds4[0..768), phase B lds4[768..1536).
    // Write stride 48B/lane -> spreads across banks (min aliasing).
    #pragma unroll
    for (int k = 0; k < 3; ++k) {
        lds4[t * 3 + k]       = dA[k];
        lds4[768 + t * 3 + k] = dB[k];
    }

    __syncthreads();

    // Coalesced nontemporal stores: 6 x 1024B-contiguous wave instructions.
    // NT: the output stream goes to HBM every replay; don't churn L2.
    long base = (long)blockIdx.x * 1536;
    #pragma unroll
    for (int k = 0; k < 6; ++k) {
        __builtin_nontemporal_store(lds4[k * 256 + t], &out4[base + k * 256 + t]);
    }
}

extern "C" void kernel_launch(void* const* d_in, const int* in_sizes, int n_in,
                              void* d_out, int out_size, void* d_ws, size_t ws_size,
                              hipStream_t stream) {
    const float* qp = (const float*)d_in[0];
    const float* qr = (const float*)d_in[1];
    const float* qy = (const float*)d_in[2];
    const float* qe = (const float*)d_in[3];
    float* out = (float*)d_out;

    int n = in_sizes[0];        // B = 2097152
    int n4 = n / 4;             // 524288 float4 per input
    int block = 256;
    int grid = n4 / (block * 2);  // 1024 blocks, 8 elements/thread

    h1_kin_kernel<<<grid, block, 0, stream>>>(
        (const f32x4*)qp, (const f32x4*)qr, (const f32x4*)qy, (const f32x4*)qe,
        (f32x4*)out, n4);
}